// Round 5
// baseline (9897.645 us; speedup 1.0000x reference)
//
#include <hip/hip_runtime.h>

typedef unsigned short u16;
typedef unsigned int   u32;

typedef __bf16 bf16x8 __attribute__((ext_vector_type(8)));
typedef float  f32x4  __attribute__((ext_vector_type(4)));

#define B_   32
#define S_   512
#define I_   512
#define H_   1024
#define NBLK 128                  // blocks; each owns H_/NBLK = 8 hidden units
#define HU   8

__device__ __forceinline__ float sigmoid_(float x) {
    return 1.0f / (1.0f + __expf(-x));
}
__device__ __forceinline__ float tanh_(float x) {
    return 2.0f / (1.0f + __expf(-2.0f * x)) - 1.0f;
}
__device__ __forceinline__ int min2(int a, int b) { return a < b ? a : b; }

// Persistent LSTM (fp32 I/O, bf16 MFMA compute).
//  - h exchange: out[] (hidden_seq) IS the ring — every (b,t,unit) line is
//    written exactly once (sc1 write-through -> IC, no dirty lines) and read
//    exactly once (plain cacheable loads, always-fresh lines -> L2-shared by
//    the 16 blocks of an XCD). No workspace ring, no per-dword IC gathers.
//  - signaling: per-wave flags (512 dwords in d_ws). Producer wave: sc1 h
//    stores -> s_waitcnt vmcnt(0) -> sc1 flag store. Consumer wave polls the
//    256 flags of its row-pair (4 dwords/lane) with s_sleep backoff; no
//    block-wide barrier on the signal path.
//  - startup: every block does buffer_wbl2+buffer_inv (flushes the pre-launch
//    memset's dirty zero/poison lines out of all 8 XCD L2s -- each XCD hosts
//    >=1 block) then a fixed ~50us delay so all flushes complete before the
//    first sc1 store lands in IC.
__global__ void __launch_bounds__(256, 1)
lstm_kernel(const float* __restrict__ X,
            const float* __restrict__ w_i, const float* __restrict__ u_i, const float* __restrict__ b_i,
            const float* __restrict__ w_f, const float* __restrict__ u_f, const float* __restrict__ b_f,
            const float* __restrict__ w_c, const float* __restrict__ u_c, const float* __restrict__ b_c,
            const float* __restrict__ w_o, const float* __restrict__ u_o, const float* __restrict__ b_o,
            float* __restrict__ out, u32* __restrict__ flags)
{
    __shared__ float gbuf[32 * 33];   // raw gates, +1 col pad

    const int tid  = threadIdx.x;
    const int wave = tid >> 6;
    const int lane = tid & 63;
    const int rt   = wave >> 1;       // row tile (batch 16*rt..)
    const int ct   = wave & 1;        // col tile (gate cols 16*ct..)
    const int quad = lane >> 4;
    const int l16  = lane & 15;
    const int hu0  = blockIdx.x * HU;

    // ---- B-operand fragments into registers (once), fp32 -> bf16 ----
    // block-local gate col: 0..31 = gate g (i,f,c,o) * 8 + unit u
    const int col = ct * 16 + l16;
    const int g   = col >> 3;
    const int u   = col & 7;
    const float* Ucol = ((g == 0) ? u_i : (g == 1) ? u_f : (g == 2) ? u_c : u_o) + hu0 + u;
    const float* Wcol = ((g == 0) ? w_i : (g == 1) ? w_f : (g == 2) ? w_c : w_o) + hu0 + u;

    bf16x8 bfr[48];                   // B[k = kb*32 + quad*8 + j][col]
    #pragma unroll
    for (int kb = 0; kb < 32; ++kb) { // K 0..1023: U rows
        #pragma unroll
        for (int j = 0; j < 8; ++j) {
            int k = kb * 32 + quad * 8 + j;
            bfr[kb][j] = (__bf16)Ucol[k * H_];
        }
    }
    #pragma unroll
    for (int kb = 32; kb < 48; ++kb) { // K 1024..1535: W rows
        #pragma unroll
        for (int j = 0; j < 8; ++j) {
            int k = kb * 32 + quad * 8 + j - 1024;
            bfr[kb][j] = (__bf16)Wcol[k * H_];
        }
    }

    // ---- update-phase ownership: thread -> (batch ub, unit uu) ----
    const int ub   = tid >> 3;        // batch 0..31
    const int uu   = tid & 7;         // unit  0..7
    const int unit = hu0 + uu;

    const float bia = b_i[unit];
    const float bif = b_f[unit];
    const float bic = b_c[unit];
    const float bio = b_o[unit];
    float cstate = 0.0f;

    const int    arow = rt * 16 + l16;                          // batch row fed to A
    const float* xrow = X   + (size_t)arow * (S_ * I_) + quad * 8;
    const float* hrow = out + (size_t)arow * (S_ * H_) + quad * 8;  // fp32 h ring

    // ---- startup flush + settle delay (see header comment) ----
    asm volatile("s_waitcnt vmcnt(0)\n\t"
                 "buffer_wbl2 sc1\n\t"
                 "s_waitcnt vmcnt(0)\n\t"
                 "buffer_inv sc1" ::: "memory");
    for (int i = 0; i < 256; ++i) __builtin_amdgcn_s_sleep(7);   // ~50 us

    const int fbase = rt * 256 + lane * 4;                 // consumer poll base
    const int fprod = rt * 256 + blockIdx.x * 2 + ct;      // this wave's flag

    for (int t = 0; t < S_; ++t) {
        // ---- x_t @ W: h-independent, fills the wait window ----
        f32x4 acc = {0.f, 0.f, 0.f, 0.f};
        const float* xk = xrow + (size_t)t * I_;
        #pragma unroll
        for (int kb = 0; kb < 16; ++kb) {
            f32x4 lo = *(const f32x4*)(xk + kb * 32);
            f32x4 hi = *(const f32x4*)(xk + kb * 32 + 4);
            bf16x8 a;
            a[0] = (__bf16)lo[0]; a[1] = (__bf16)lo[1];
            a[2] = (__bf16)lo[2]; a[3] = (__bf16)lo[3];
            a[4] = (__bf16)hi[0]; a[5] = (__bf16)hi[1];
            a[6] = (__bf16)hi[2]; a[7] = (__bf16)hi[3];
            acc = __builtin_amdgcn_mfma_f32_16x16x32_bf16(a, bfr[32 + kb], acc, 0, 0, 0);
        }

        if (t > 0) {
            // ---- wait: all 256 producer waves of row-pair rt at step >= t ----
            for (;;) {
                int m0 = (int)__hip_atomic_load(flags + fbase + 0, __ATOMIC_RELAXED, __HIP_MEMORY_SCOPE_AGENT);
                int m1 = (int)__hip_atomic_load(flags + fbase + 1, __ATOMIC_RELAXED, __HIP_MEMORY_SCOPE_AGENT);
                int m2 = (int)__hip_atomic_load(flags + fbase + 2, __ATOMIC_RELAXED, __HIP_MEMORY_SCOPE_AGENT);
                int m3 = (int)__hip_atomic_load(flags + fbase + 3, __ATOMIC_RELAXED, __HIP_MEMORY_SCOPE_AGENT);
                if (min2(min2(m0, m1), min2(m2, m3)) >= t) break;
                __builtin_amdgcn_s_sleep(2);
            }
            asm volatile("" ::: "memory");   // no hoisting h loads above the poll

            // ---- h(t-1) @ U: plain cacheable fp32 loads from out ----
            const float* hk = hrow + (size_t)(t - 1) * H_;
            #pragma unroll
            for (int kb = 0; kb < 32; ++kb) {
                f32x4 lo = *(const f32x4*)(hk + kb * 32);
                f32x4 hi = *(const f32x4*)(hk + kb * 32 + 4);
                bf16x8 a;
                a[0] = (__bf16)lo[0]; a[1] = (__bf16)lo[1];
                a[2] = (__bf16)lo[2]; a[3] = (__bf16)lo[3];
                a[4] = (__bf16)hi[0]; a[5] = (__bf16)hi[1];
                a[6] = (__bf16)hi[2]; a[7] = (__bf16)hi[3];
                acc = __builtin_amdgcn_mfma_f32_16x16x32_bf16(a, bfr[kb], acc, 0, 0, 0);
            }
        }
        // (t == 0: h0 = 0 contributes nothing — skip poll and h@U entirely)

        // C/D layout: D[row = quad*4 + r][col = lane&15] (+16 per tile)
        {
            const int r0 = rt * 16 + quad * 4;
            #pragma unroll
            for (int r = 0; r < 4; ++r)
                gbuf[(r0 + r) * 33 + col] = acc[r];
        }
        __syncthreads();   // near-free drain: all vmem already consumed

        // gates -> c,h update (c stays in an fp32 register all 512 steps)
        {
            float gi = gbuf[ub * 33 + uu]      + bia;
            float gf = gbuf[ub * 33 + 8 + uu]  + bif;
            float gc = gbuf[ub * 33 + 16 + uu] + bic;
            float go = gbuf[ub * 33 + 24 + uu] + bio;
            float it  = sigmoid_(gi);
            float ft  = sigmoid_(gf);
            float ctl = tanh_(gc);
            float ot  = sigmoid_(go);
            cstate = ft * cstate + it * ctl;
            float h = ot * tanh_(cstate);

            // h -> out (hidden_seq), sc1 write-through to IC (consumer-visible)
            u32* hp = (u32*)(out + (size_t)ub * (S_ * H_) + (size_t)t * H_ + unit);
            __hip_atomic_store(hp, __builtin_bit_cast(u32, h),
                               __ATOMIC_RELAXED, __HIP_MEMORY_SCOPE_AGENT);
            asm volatile("s_waitcnt vmcnt(0)" ::: "memory");   // drain this wave's h
            if (lane == 0)
                __hip_atomic_store(flags + fprod, (u32)(t + 1),
                                   __ATOMIC_RELAXED, __HIP_MEMORY_SCOPE_AGENT);
            if (t == S_ - 1) {
                out[(size_t)B_ * S_ * H_ + ub * H_ + unit] = h;                  // h_t
                out[(size_t)B_ * S_ * H_ + B_ * H_ + ub * H_ + unit] = cstate;   // c_t
            }
        }
        __syncthreads();   // gbuf WAR protection for next iteration
    }
}

extern "C" void kernel_launch(void* const* d_in, const int* in_sizes, int n_in,
                              void* d_out, int out_size, void* d_ws, size_t ws_size,
                              hipStream_t stream) {
    const float* X   = (const float*)d_in[0];
    const float* w_i = (const float*)d_in[1];
    const float* u_i = (const float*)d_in[2];
    const float* b_i = (const float*)d_in[3];
    const float* w_f = (const float*)d_in[4];
    const float* u_f = (const float*)d_in[5];
    const float* b_f = (const float*)d_in[6];
    const float* w_c = (const float*)d_in[7];
    const float* u_c = (const float*)d_in[8];
    const float* b_c = (const float*)d_in[9];
    const float* w_o = (const float*)d_in[10];
    const float* u_o = (const float*)d_in[11];
    const float* b_o = (const float*)d_in[12];
    float* out = (float*)d_out;

    // d_ws: per-wave flags, 2 row-pairs x 128 blocks x 2 waves = 512 dwords.
    // Poison 0xAAAAAAAA is negative under signed compare -> never >= t.
    u32* flags = (u32*)d_ws;

    hipLaunchKernelGGL(lstm_kernel, dim3(NBLK), dim3(256), 0, stream,
                       X, w_i, u_i, b_i, w_f, u_f, b_f, w_c, u_c, b_c,
                       w_o, u_o, b_o, out, flags);
}